// Round 6
// baseline (571.541 us; speedup 1.0000x reference)
//
#include <hip/hip_runtime.h>
#include <hip/hip_bf16.h>

#define B_   4
#define T_   2048
#define C_   1024
#define NH   16
#define HD   64

typedef unsigned short u16;
typedef short bf16x8 __attribute__((ext_vector_type(8)));   // 8 bf16 = 4 VGPR
typedef short bf16x4 __attribute__((ext_vector_type(4)));   // 4 bf16 = 2 VGPR
typedef float f32x4  __attribute__((ext_vector_type(4)));

#define MFMA_BF16(a, b, c) __builtin_amdgcn_mfma_f32_16x16x32_bf16((a), (b), (c), 0, 0, 0)

__device__ __forceinline__ u16 f2bf(float f) {
    unsigned u = __float_as_uint(f);
    return (u16)((u + 0x7FFFu + ((u >> 16) & 1u)) >> 16);   // RNE
}
__device__ __forceinline__ bf16x8 pack8(float4 f0, float4 f1) {
    bf16x8 r;
    r[0] = (short)f2bf(f0.x); r[1] = (short)f2bf(f0.y);
    r[2] = (short)f2bf(f0.z); r[3] = (short)f2bf(f0.w);
    r[4] = (short)f2bf(f1.x); r[5] = (short)f2bf(f1.y);
    r[6] = (short)f2bf(f1.z); r[7] = (short)f2bf(f1.w);
    return r;
}
__device__ __forceinline__ bf16x4 pack4(f32x4 v) {
    bf16x4 r;
    r[0] = (short)f2bf(v[0]); r[1] = (short)f2bf(v[1]);
    r[2] = (short)f2bf(v[2]); r[3] = (short)f2bf(v[3]);
    return r;
}

// async 16B global -> LDS (only used for one-shot Q staging; drained at first barrier)
__device__ __forceinline__ void gl2lds16(const void* g, void* l) {
    __builtin_amdgcn_global_load_lds(
        (const __attribute__((address_space(1))) void*)g,
        (__attribute__((address_space(3))) void*)l,
        16, 0, 0);
}

// =====================================================================
// cast_x: fp32 [8192*1024] -> bf16
// =====================================================================
__global__ __launch_bounds__(256) void cast_x(
    const float* __restrict__ x, u16* __restrict__ xb)
{
    int i = (blockIdx.x * 256 + threadIdx.x) * 8;
    float4 f0 = *reinterpret_cast<const float4*>(&x[i]);
    float4 f1 = *reinterpret_cast<const float4*>(&x[i + 4]);
    *reinterpret_cast<bf16x8*>(&xb[i]) = pack8(f0, f1);
}

// =====================================================================
// transpose_w: src fp32 [R][C] -> dst bf16 [C][R]
// =====================================================================
__global__ __launch_bounds__(256) void transpose_w(
    const float* __restrict__ src, u16* __restrict__ dst, int R, int Ccols)
{
    __shared__ float tile[32][33];
    const int c0 = blockIdx.x * 32, r0 = blockIdx.y * 32;
    const int tx = threadIdx.x, ty = threadIdx.y;
#pragma unroll
    for (int i = 0; i < 4; ++i)
        tile[ty + 8 * i][tx] = src[(size_t)(r0 + ty + 8 * i) * Ccols + c0 + tx];
    __syncthreads();
#pragma unroll
    for (int i = 0; i < 4; ++i)
        dst[(size_t)(c0 + ty + 8 * i) * R + r0 + tx] = f2bf(tile[tx][ty + 8 * i]);
}

// =====================================================================
// qkv_gemm_mfma v4: reg-staged dbuf K-loop, BK=32, ONE barrier/iter.
// C[8192,3072] = xb * wqT^T + b -> scatter Q(*0.125)/K/V [B,NH,T,HD] bf16.
// grid (24,64), block 256.
// =====================================================================
__global__ __launch_bounds__(256, 3) void qkv_gemm_mfma(
    const u16* __restrict__ xb, const u16* __restrict__ wqT,
    const float* __restrict__ bqkv,
    u16* __restrict__ Qo, u16* __restrict__ Ko, u16* __restrict__ Vo)
{
    __shared__ __attribute__((aligned(16))) u16 As[2][128 * 32];  // 2 x 8 KB
    __shared__ __attribute__((aligned(16))) u16 Bs[2][128 * 32];  // 2 x 8 KB

    const int t = threadIdx.x, lane = t & 63, w = t >> 6;
    const int n = lane & 15, quad = lane >> 4;
    const int wr = w >> 1, wc = w & 1;
    const int m0 = blockIdx.y * 128, n0 = blockIdx.x * 128;

    f32x4 acc[4][4] = {};
    float4 areg[2], breg[2];

    // prologue: tile k0=0 -> regs -> LDS buf0
#pragma unroll
    for (int p = 0; p < 2; ++p) {
        int id = t + p * 256;
        int row = id >> 2, c = (id & 3) ^ (row & 3);
        areg[p] = *reinterpret_cast<const float4*>(&xb[(size_t)(m0 + row) * 1024 + c * 8]);
        breg[p] = *reinterpret_cast<const float4*>(&wqT[(size_t)(n0 + row) * 1024 + c * 8]);
    }
#pragma unroll
    for (int p = 0; p < 2; ++p) {
        int id = t + p * 256;
        *reinterpret_cast<float4*>(&As[0][id * 8]) = areg[p];
        *reinterpret_cast<float4*>(&Bs[0][id * 8]) = breg[p];
    }

    for (int k0 = 0; k0 < 1024; k0 += 32) {
        const int cur = (k0 >> 5) & 1;
        __syncthreads();   // buf[cur] visible; prior readers of buf[cur^1] done

        const bool hn = (k0 + 32) < 1024;
        if (hn) {          // prefetch next tile into VGPRs (no LDS alias -> no stall)
#pragma unroll
            for (int p = 0; p < 2; ++p) {
                int id = t + p * 256;
                int row = id >> 2, c = (id & 3) ^ (row & 3);
                areg[p] = *reinterpret_cast<const float4*>(&xb[(size_t)(m0 + row) * 1024 + k0 + 32 + c * 8]);
                breg[p] = *reinterpret_cast<const float4*>(&wqT[(size_t)(n0 + row) * 1024 + k0 + 32 + c * 8]);
            }
        }

        const int slot = (quad ^ (n & 3)) * 8;
        bf16x8 a[4], b[4];
#pragma unroll
        for (int i = 0; i < 4; ++i)
            a[i] = *reinterpret_cast<const bf16x8*>(&As[cur][(wr * 64 + i * 16 + n) * 32 + slot]);
#pragma unroll
        for (int j = 0; j < 4; ++j)
            b[j] = *reinterpret_cast<const bf16x8*>(&Bs[cur][(wc * 64 + j * 16 + n) * 32 + slot]);
#pragma unroll
        for (int i = 0; i < 4; ++i)
#pragma unroll
            for (int j = 0; j < 4; ++j)
                acc[i][j] = MFMA_BF16(a[i], b[j], acc[i][j]);

        if (hn) {          // vmcnt wait lands here, after a full tile of compute
#pragma unroll
            for (int p = 0; p < 2; ++p) {
                int id = t + p * 256;
                *reinterpret_cast<float4*>(&As[cur ^ 1][id * 8]) = areg[p];
                *reinterpret_cast<float4*>(&Bs[cur ^ 1][id * 8]) = breg[p];
            }
        }
    }

    // epilogue: bias + scatter (wave half = 64 cols = one head, one "which")
    const int colbase = n0 + wc * 64;
    const int which = colbase >> 10;
    const int h = (colbase & 1023) >> 6;
    u16* dst = (which == 0) ? Qo : ((which == 1) ? Ko : Vo);
    const float sc = (which == 0) ? 0.125f : 1.0f;   // fold 1/sqrt(HD) into Q
#pragma unroll
    for (int i = 0; i < 4; ++i) {
#pragma unroll
        for (int r = 0; r < 4; ++r) {
            int m = m0 + wr * 64 + i * 16 + quad * 4 + r;
            int bb = m >> 11, trow = m & 2047;
            size_t obase = (((size_t)(bb * NH + h)) * 2048 + trow) * 64;
#pragma unroll
            for (int j = 0; j < 4; ++j) {
                float v = acc[i][j][r] + bqkv[colbase + j * 16 + n];
                dst[obase + j * 16 + n] = f2bf(v * sc);
            }
        }
    }
}

// =====================================================================
// transpose_v: V [bh][2048][64] bf16 -> Vt [bh][64][2048] bf16
// =====================================================================
__global__ __launch_bounds__(256) void transpose_v(
    const u16* __restrict__ V, u16* __restrict__ Vt)
{
    __shared__ u16 tile[64 * 82];
    const int bh = blockIdx.y, t0 = blockIdx.x * 64;
    const int t = threadIdx.x;
    const u16* src = V + (size_t)bh * 131072 + (size_t)t0 * 64;
    u16* dst = Vt + (size_t)bh * 131072 + t0;
#pragma unroll
    for (int p = 0; p < 2; ++p) {
        int id = t + p * 256;
        int row = id >> 3, seg = id & 7;
        ushort4 u0 = *reinterpret_cast<const ushort4*>(&src[row * 64 + seg * 8]);
        ushort4 u1 = *reinterpret_cast<const ushort4*>(&src[row * 64 + seg * 8 + 4]);
        u16* tp = &tile[row * 82 + seg * 8];
        tp[0] = u0.x; tp[1] = u0.y; tp[2] = u0.z; tp[3] = u0.w;
        tp[4] = u1.x; tp[5] = u1.y; tp[6] = u1.z; tp[7] = u1.w;
    }
    __syncthreads();
#pragma unroll
    for (int p = 0; p < 2; ++p) {
        int id = t + p * 256;
        int d = id >> 3, ks = id & 7;
        u16 u[8];
#pragma unroll
        for (int j = 0; j < 8; ++j) u[j] = tile[(ks * 8 + j) * 82 + d];
        *reinterpret_cast<ushort4*>(&dst[(size_t)d * 2048 + ks * 8])     = make_ushort4(u[0], u[1], u[2], u[3]);
        *reinterpret_cast<ushort4*>(&dst[(size_t)d * 2048 + ks * 8 + 4]) = make_ushort4(u[4], u[5], u[6], u[7]);
    }
}

// =====================================================================
// attn_mfma v4: S^T formulation + reg-staged dbuf K/V + Ps aliased into Qs.
// LDS = 16(QPs) + 16(Ks[2]) + 16(Vs[2]) = 48 KB -> 3 blocks/CU, 1 barrier/iter.
// Wave w's P^T strip lives in wave w's OWN Qs rows [w*32, w*32+32) —
// Qs is dead after the kt==0 qa load; no cross-wave overlap by construction.
// grid (16, 64), block 256 (4 waves x 32 q rows each).
// =====================================================================
__global__ __launch_bounds__(256, 3) void attn_mfma(
    const u16* __restrict__ Q, const u16* __restrict__ K,
    const u16* __restrict__ Vt, u16* __restrict__ Y)
{
    const int qt = (int)gridDim.x - 1 - (int)blockIdx.x;   // longest blocks first
    const int bh = blockIdx.y;
    const int q0 = qt * 128;
    const int b = bh >> 4, h = bh & 15;
    const size_t base = (size_t)bh * (T_ * HD);

    __shared__ __attribute__((aligned(16))) u16 QPs[128 * 64];    // 16 KB: Q then per-wave P^T
    __shared__ __attribute__((aligned(16))) u16 Ks[2][64 * 64];   // 16 KB
    __shared__ __attribute__((aligned(16))) u16 Vs[2][64 * 64];   // 16 KB

    const int t = threadIdx.x, lane = t & 63, w = t >> 6;
    const int n = lane & 15, quad = lane >> 4;
    const int tmask = t & ~63;
    const int qw_lo = q0 + w * 32;
    const int qw_hi = qw_lo + 31;

    // one-shot Q staging via DMA (drained by the first barrier's vmcnt(0))
#pragma unroll
    for (int p = 0; p < 4; ++p) {
        int id = t + p * 256;
        int row = id >> 3, c = (id & 7) ^ (row & 7);
        gl2lds16(&Q[base + (size_t)(q0 + row) * 64 + c * 8], &QPs[(tmask + p * 256) * 8]);
    }

    // K/V tile 0 -> regs -> LDS buf0
    float4 kreg[2], vreg[2];
#pragma unroll
    for (int p = 0; p < 2; ++p) {
        int id = t + p * 256;
        int row = id >> 3, c = (id & 7) ^ (row & 7);
        kreg[p] = *reinterpret_cast<const float4*>(&K[base + (size_t)row * 64 + c * 8]);
        vreg[p] = *reinterpret_cast<const float4*>(&Vt[base + (size_t)row * 2048 + c * 8]);
    }
#pragma unroll
    for (int p = 0; p < 2; ++p) {
        int id = t + p * 256;
        *reinterpret_cast<float4*>(&Ks[0][id * 8]) = kreg[p];
        *reinterpret_cast<float4*>(&Vs[0][id * 8]) = vreg[p];
    }

    f32x4 o[2][4] = {};
    float mst[2] = {-1e30f, -1e30f}, lst[2] = {0.f, 0.f};
    bf16x8 qa[2][2];

    const int nkt = 2 * qt + 2;
    for (int kt = 0; kt < nkt; ++kt) {
        const int k0 = kt * 64;
        const int cur = kt & 1;
        __syncthreads();   // buf[cur] writes visible; prior readers of buf[cur^1] done

        if (kt == 0) {     // load Q frags once; wave w reads ONLY its own rows
#pragma unroll
            for (int nt2 = 0; nt2 < 2; ++nt2)
#pragma unroll
                for (int dh = 0; dh < 2; ++dh) {
                    int row = w * 32 + nt2 * 16 + n;
                    int slot = (quad + dh * 4) ^ (n & 7);
                    qa[nt2][dh] = *reinterpret_cast<const bf16x8*>(&QPs[row * 64 + slot * 8]);
                }
        }

        const bool hn = (kt + 1) < nkt;
        if (hn) {          // prefetch next K/V tile into VGPRs
            const int kp = k0 + 64;
#pragma unroll
            for (int p = 0; p < 2; ++p) {
                int id = t + p * 256;
                int row = id >> 3, c = (id & 7) ^ (row & 7);
                kreg[p] = *reinterpret_cast<const float4*>(&K[base + (size_t)(kp + row) * 64 + c * 8]);
                vreg[p] = *reinterpret_cast<const float4*>(&Vt[base + (size_t)row * 2048 + kp + c * 8]);
            }
        }

        if (k0 <= qw_hi) {   // wave-active (fully-masked tiles skip compute only)
            const u16* Kc = Ks[cur];
            const u16* Vc = Vs[cur];

            // ---- S^T = K Q^T : strip [64 k][32 q] ----
            bf16x8 kf[4][2];
#pragma unroll
            for (int mt = 0; mt < 4; ++mt)
#pragma unroll
                for (int dh = 0; dh < 2; ++dh) {
                    int row = mt * 16 + n;
                    int slot = (quad + dh * 4) ^ (n & 7);
                    kf[mt][dh] = *reinterpret_cast<const bf16x8*>(&Kc[row * 64 + slot * 8]);
                }
            f32x4 s2[2][4] = {};
#pragma unroll
            for (int nt2 = 0; nt2 < 2; ++nt2)
#pragma unroll
                for (int mt = 0; mt < 4; ++mt)
#pragma unroll
                    for (int dh = 0; dh < 2; ++dh)
                        s2[nt2][mt] = MFMA_BF16(kf[mt][dh], qa[nt2][dh], s2[nt2][mt]);

            // causal mask: needed when tile's max k exceeds wave's LOWEST q
            if (k0 + 63 > qw_lo) {
#pragma unroll
                for (int nt2 = 0; nt2 < 2; ++nt2) {
                    int qrel = (qw_lo + nt2 * 16 + n) - k0;
#pragma unroll
                    for (int mt = 0; mt < 4; ++mt)
#pragma unroll
                        for (int r = 0; r < 4; ++r)
                            if (mt * 16 + quad * 4 + r > qrel) s2[nt2][mt][r] = -1e30f;
                }
            }

            // ---- lane-local online softmax (lane owns q = nt2*16 + n) ----
            float alpha[2];
#pragma unroll
            for (int nt2 = 0; nt2 < 2; ++nt2) {
                float mx = -1e30f;
#pragma unroll
                for (int mt = 0; mt < 4; ++mt)
                    mx = fmaxf(mx, fmaxf(fmaxf(s2[nt2][mt][0], s2[nt2][mt][1]),
                                         fmaxf(s2[nt2][mt][2], s2[nt2][mt][3])));
                mx = fmaxf(mx, __shfl_xor(mx, 16, 64));
                mx = fmaxf(mx, __shfl_xor(mx, 32, 64));
                float mnew = fmaxf(mst[nt2], mx);
                alpha[nt2] = __expf(mst[nt2] - mnew);
                float rs = 0.f;
#pragma unroll
                for (int mt = 0; mt < 4; ++mt)
#pragma unroll
                    for (int r = 0; r < 4; ++r) {
                        float p = __expf(s2[nt2][mt][r] - mnew);
                        s2[nt2][mt][r] = p;
                        rs += p;
                    }
                rs += __shfl_xor(rs, 16, 64);
                rs += __shfl_xor(rs, 32, 64);
                lst[nt2] = lst[nt2] * alpha[nt2] + rs;
                mst[nt2] = mnew;
            }

            // ---- P^T -> wave's own QPs rows (XOR chunk swizzle, zero pad) ----
            // write: q_local = nt2*16+n, k = mt*16+quad*4+r -> chunk kc = mt*2+(quad>>1),
            //        slot = kc ^ (n&7), half = (quad&1)*4
#pragma unroll
            for (int nt2 = 0; nt2 < 2; ++nt2)
#pragma unroll
                for (int mt = 0; mt < 4; ++mt) {
                    int kc = mt * 2 + (quad >> 1);
                    int off = (w * 32 + nt2 * 16 + n) * 64 + (kc ^ (n & 7)) * 8 + (quad & 1) * 4;
                    *reinterpret_cast<bf16x4*>(&QPs[off]) = pack4(s2[nt2][mt]);
                }

            // ---- rescale O, then O^T += V^T P^T ----
#pragma unroll
            for (int nt2 = 0; nt2 < 2; ++nt2)
#pragma unroll
                for (int dt = 0; dt < 4; ++dt)
                    o[nt2][dt] *= alpha[nt2];

            bf16x8 pf[2][2];
#pragma unroll
            for (int nt2 = 0; nt2 < 2; ++nt2)
#pragma unroll
                for (int kh = 0; kh < 2; ++kh) {
                    int kc = kh * 4 + quad;
                    int off = (w * 32 + nt2 * 16 + n) * 64 + (kc ^ (n & 7)) * 8;
                    pf[nt2][kh] = *reinterpret_cast<const bf16x8*>(&QPs[off]);
                }
            bf16x8 vf[4][2];
#pragma unroll
            for (int dt = 0; dt < 4; ++dt)
#pragma unroll
                for (int kh = 0; kh < 2; ++kh) {
                    int row = dt * 16 + n;
                    int slot = (quad + kh * 4) ^ (n & 7);
                    vf[dt][kh] = *reinterpret_cast<const bf16x8*>(&Vc[row * 64 + slot * 8]);
                }
#pragma unroll
            for (int nt2 = 0; nt2 < 2; ++nt2)
#pragma unroll
                for (int dt = 0; dt < 4; ++dt)
#pragma unroll
                    for (int kh = 0; kh < 2; ++kh)
                        o[nt2][dt] = MFMA_BF16(vf[dt][kh], pf[nt2][kh], o[nt2][dt]);
        }

        if (hn) {          // stage prefetched tile; vmcnt wait here, after compute
#pragma unroll
            for (int p = 0; p < 2; ++p) {
                int id = t + p * 256;
                *reinterpret_cast<float4*>(&Ks[cur ^ 1][id * 8]) = kreg[p];
                *reinterpret_cast<float4*>(&Vs[cur ^ 1][id * 8]) = vreg[p];
            }
        }
    }

    // epilogue: Y[b,q,h,d] = O^T / l
#pragma unroll
    for (int nt2 = 0; nt2 < 2; ++nt2) {
        float inv = 1.f / lst[nt2];
        int qg = qw_lo + nt2 * 16 + n;
        size_t ob = (((size_t)(b * 2048 + qg)) * NH + h) * 64;
#pragma unroll
        for (int dt = 0; dt < 4; ++dt) {
            ushort4 st = make_ushort4(f2bf(o[nt2][dt][0] * inv), f2bf(o[nt2][dt][1] * inv),
                                      f2bf(o[nt2][dt][2] * inv), f2bf(o[nt2][dt][3] * inv));
            *reinterpret_cast<ushort4*>(&Y[ob + dt * 16 + quad * 4]) = st;
        }
    }
}

// =====================================================================
// proj_gemm_mfma v4: reg-staged dbuf, BK=32. out = Y * wpT^T + b. grid (8,64).
// =====================================================================
__global__ __launch_bounds__(256, 3) void proj_gemm_mfma(
    const u16* __restrict__ A, const u16* __restrict__ BT,
    const float* __restrict__ bias, float* __restrict__ out)
{
    __shared__ __attribute__((aligned(16))) u16 As[2][128 * 32];
    __shared__ __attribute__((aligned(16))) u16 Bs[2][128 * 32];

    const int t = threadIdx.x, lane = t & 63, w = t >> 6;
    const int n = lane & 15, quad = lane >> 4;
    const int wr = w >> 1, wc = w & 1;
    const int m0 = blockIdx.y * 128, n0 = blockIdx.x * 128;

    f32x4 acc[4][4] = {};
    float4 areg[2], breg[2];

#pragma unroll
    for (int p = 0; p < 2; ++p) {
        int id = t + p * 256;
        int row = id >> 2, c = (id & 3) ^ (row & 3);
        areg[p] = *reinterpret_cast<const float4*>(&A[(size_t)(m0 + row) * 1024 + c * 8]);
        breg[p] = *reinterpret_cast<const float4*>(&BT[(size_t)(n0 + row) * 1024 + c * 8]);
    }
#pragma unroll
    for (int p = 0; p < 2; ++p) {
        int id = t + p * 256;
        *reinterpret_cast<float4*>(&As[0][id * 8]) = areg[p];
        *reinterpret_cast<float4*>(&Bs[0][id * 8]) = breg[p];
    }

    for (int k0 = 0; k0 < 1024; k0 += 32) {
        const int cur = (k0 >> 5) & 1;
        __syncthreads();

        const bool hn = (k0 + 32) < 1024;
        if (hn) {
#pragma unroll
            for (int p = 0; p < 2; ++p) {
                int id = t + p * 256;
                int row = id >> 2, c = (id & 3) ^ (row & 3);
                areg[p] = *reinterpret_cast<const float4*>(&A[(size_t)(m0 + row) * 1024 + k0 + 32 + c * 8]);
                breg[p] = *reinterpret_cast<const float4*>(&BT[(size_t)(n0 + row) * 1024 + k0 + 32 + c * 8]);
            }
        }

        const int slot = (quad ^ (n & 3)) * 8;
        bf16x8 a[4], b[4];
#pragma unroll
        for (int i = 0; i < 4; ++i)
            a[i] = *reinterpret_cast<const bf16x8*>(&As[cur][(wr * 64 + i * 16 + n) * 32 + slot]);
#pragma unroll
        for (int j = 0; j < 4; ++j)
            b[j] = *reinterpret_cast<const bf16x8*>(&Bs[cur][(wc * 64 + j * 16 + n) * 32 + slot]);
#pragma unroll
        for (int i = 0; i < 4; ++i)
#pragma unroll
            for (int j = 0; j < 4; ++j)
                acc[i][j] = MFMA_BF16(a[i], b[j], acc[i][j]);

        if (hn) {
#pragma unroll
            for (int p = 0; p < 2; ++p) {
                int id = t + p * 256;
                *reinterpret_cast<float4*>(&As[cur ^ 1][id * 8]) = areg[p];
                *reinterpret_cast<float4*>(&Bs[cur ^ 1][id * 8]) = breg[p];
            }
        }
    }

#pragma unroll
    for (int i = 0; i < 4; ++i)
#pragma unroll
        for (int r = 0; r < 4; ++r) {
            int m = m0 + wr * 64 + i * 16 + quad * 4 + r;
#pragma unroll
            for (int j = 0; j < 4; ++j) {
                int col = n0 + wc * 64 + j * 16 + n;
                out[(size_t)m * 1024 + col] = acc[i][j][r] + bias[col];
            }
        }
}

// =====================================================================
// Workspace overlay (<= 64 MB ws + d_out used as pre-proj scratch):
//   ws [0,16M): Q      ... later wpT (after attn)
//   ws [16,32M): K
//   ws [32,48M): V     ... later Y (after transpose_v)
//   ws [48,54M): wqT   ... [48,64M): Vt (after qkv)
//   d_out [0,16M): xb (bf16 x) — dead before proj writes d_out
// =====================================================================
extern "C" void kernel_launch(void* const* d_in, const int* in_sizes, int n_in,
                              void* d_out, int out_size, void* d_ws, size_t ws_size,
                              hipStream_t stream) {
    const float* x      = (const float*)d_in[0];
    const float* w_qkv  = (const float*)d_in[1];
    const float* b_qkv  = (const float*)d_in[2];
    const float* w_proj = (const float*)d_in[3];
    const float* b_proj = (const float*)d_in[4];
    float* out = (float*)d_out;

    const size_t E16 = 8388608;
    u16* ws  = (u16*)d_ws;
    u16* Qp  = ws;
    u16* Kp  = ws + E16;
    u16* Vp  = ws + 2 * E16;
    u16* wqT = ws + 3 * E16;
    u16* VtP = ws + 3 * E16;
    u16* Yp  = ws + 2 * E16;
    u16* wpT = ws;
    u16* xb  = (u16*)d_out;                // scratch inside d_out, dead before proj

    cast_x<<<dim3(4096), 256, 0, stream>>>(x, xb);
    transpose_w<<<dim3(96, 32), dim3(32, 8), 0, stream>>>(w_qkv, wqT, 1024, 3072);
    qkv_gemm_mfma<<<dim3(24, 64), 256, 0, stream>>>(xb, wqT, b_qkv, Qp, Kp, Vp);
    transpose_v<<<dim3(32, 64), 256, 0, stream>>>(Vp, VtP);
    attn_mfma<<<dim3(16, 64), 256, 0, stream>>>(Qp, Kp, VtP, Yp);
    transpose_w<<<dim3(32, 32), dim3(32, 8), 0, stream>>>(w_proj, wpT, 1024, 1024);
    proj_gemm_mfma<<<dim3(8, 64), 256, 0, stream>>>(Yp, wpT, b_proj, out);
}

// Round 7
// 279.217 us; speedup vs baseline: 2.0469x; 2.0469x over previous
//
#include <hip/hip_runtime.h>
#include <hip/hip_bf16.h>

#define B_   4
#define T_   2048
#define C_   1024
#define NH   16
#define HD   64

typedef unsigned short u16;
typedef short bf16x8 __attribute__((ext_vector_type(8)));   // 8 bf16 = 4 VGPR
typedef short bf16x4 __attribute__((ext_vector_type(4)));   // 4 bf16 = 2 VGPR
typedef float f32x4  __attribute__((ext_vector_type(4)));

#define MFMA_BF16(a, b, c) __builtin_amdgcn_mfma_f32_16x16x32_bf16((a), (b), (c), 0, 0, 0)

__device__ __forceinline__ u16 f2bf(float f) {
    unsigned u = __float_as_uint(f);
    return (u16)((u + 0x7FFFu + ((u >> 16) & 1u)) >> 16);   // RNE
}
__device__ __forceinline__ bf16x8 pack8(float4 f0, float4 f1) {
    bf16x8 r;
    r[0] = (short)f2bf(f0.x); r[1] = (short)f2bf(f0.y);
    r[2] = (short)f2bf(f0.z); r[3] = (short)f2bf(f0.w);
    r[4] = (short)f2bf(f1.x); r[5] = (short)f2bf(f1.y);
    r[6] = (short)f2bf(f1.z); r[7] = (short)f2bf(f1.w);
    return r;
}
__device__ __forceinline__ bf16x4 pack4(f32x4 v) {
    bf16x4 r;
    r[0] = (short)f2bf(v[0]); r[1] = (short)f2bf(v[1]);
    r[2] = (short)f2bf(v[2]); r[3] = (short)f2bf(v[3]);
    return r;
}

// async 16B global -> LDS (DMA; LDS dest = wave-uniform base + lane*16)
__device__ __forceinline__ void gl2lds16(const void* g, void* l) {
    __builtin_amdgcn_global_load_lds(
        (const __attribute__((address_space(1))) void*)g,
        (__attribute__((address_space(3))) void*)l,
        16, 0, 0);
}

// =====================================================================
// cast_x: fp32 [8192*1024] -> bf16
// =====================================================================
__global__ __launch_bounds__(256) void cast_x(
    const float* __restrict__ x, u16* __restrict__ xb)
{
    int i = (blockIdx.x * 256 + threadIdx.x) * 8;
    float4 f0 = *reinterpret_cast<const float4*>(&x[i]);
    float4 f1 = *reinterpret_cast<const float4*>(&x[i + 4]);
    *reinterpret_cast<bf16x8*>(&xb[i]) = pack8(f0, f1);
}

// =====================================================================
// transpose_w: src fp32 [R][C] -> dst bf16 [C][R]
// =====================================================================
__global__ __launch_bounds__(256) void transpose_w(
    const float* __restrict__ src, u16* __restrict__ dst, int R, int Ccols)
{
    __shared__ float tile[32][33];
    const int c0 = blockIdx.x * 32, r0 = blockIdx.y * 32;
    const int tx = threadIdx.x, ty = threadIdx.y;
#pragma unroll
    for (int i = 0; i < 4; ++i)
        tile[ty + 8 * i][tx] = src[(size_t)(r0 + ty + 8 * i) * Ccols + c0 + tx];
    __syncthreads();
#pragma unroll
    for (int i = 0; i < 4; ++i)
        dst[(size_t)(c0 + ty + 8 * i) * R + r0 + tx] = f2bf(tile[tx][ty + 8 * i]);
}

// =====================================================================
// qkv_gemm_mfma (round-3 proven version): BK=32, gl2lds16, 2 barriers/iter.
// C[8192,3072] = xb * wqT^T + b -> scatter Q(*0.125)/K/V [B,NH,T,HD] bf16.
// grid (24,64), block 256.
// =====================================================================
__global__ __launch_bounds__(256, 3) void qkv_gemm_mfma(
    const u16* __restrict__ xb, const u16* __restrict__ wqT,
    const float* __restrict__ bqkv,
    u16* __restrict__ Qo, u16* __restrict__ Ko, u16* __restrict__ Vo)
{
    __shared__ __attribute__((aligned(16))) u16 As[128 * 32];
    __shared__ __attribute__((aligned(16))) u16 Bs[128 * 32];

    const int t = threadIdx.x, lane = t & 63, w = t >> 6;
    const int n = lane & 15, quad = lane >> 4;
    const int wr = w >> 1, wc = w & 1;
    const int m0 = blockIdx.y * 128, n0 = blockIdx.x * 128;
    const int tmask = t & ~63;

    f32x4 acc[4][4] = {};

    for (int k0 = 0; k0 < 1024; k0 += 32) {
        __syncthreads();
#pragma unroll
        for (int p = 0; p < 2; ++p) {
            int id = t + p * 256;
            int row = id >> 2, c = (id & 3) ^ (row & 3);
            gl2lds16(&xb[(size_t)(m0 + row) * 1024 + k0 + c * 8], &As[(tmask + p * 256) * 8]);
            gl2lds16(&wqT[(size_t)(n0 + row) * 1024 + k0 + c * 8], &Bs[(tmask + p * 256) * 8]);
        }
        __syncthreads();

        const int slot = (quad ^ (n & 3)) * 8;
        bf16x8 a[4], b[4];
#pragma unroll
        for (int i = 0; i < 4; ++i)
            a[i] = *reinterpret_cast<const bf16x8*>(&As[(wr * 64 + i * 16 + n) * 32 + slot]);
#pragma unroll
        for (int j = 0; j < 4; ++j)
            b[j] = *reinterpret_cast<const bf16x8*>(&Bs[(wc * 64 + j * 16 + n) * 32 + slot]);
#pragma unroll
        for (int i = 0; i < 4; ++i)
#pragma unroll
            for (int j = 0; j < 4; ++j)
                acc[i][j] = MFMA_BF16(a[i], b[j], acc[i][j]);
    }

    // epilogue: bias + scatter (wave half = 64 cols = one head, one "which")
    const int colbase = n0 + wc * 64;
    const int which = colbase >> 10;
    const int h = (colbase & 1023) >> 6;
    u16* dst = (which == 0) ? Qo : ((which == 1) ? Ko : Vo);
    const float sc = (which == 0) ? 0.125f : 1.0f;   // fold 1/sqrt(HD) into Q
#pragma unroll
    for (int i = 0; i < 4; ++i) {
#pragma unroll
        for (int r = 0; r < 4; ++r) {
            int m = m0 + wr * 64 + i * 16 + quad * 4 + r;
            int bb = m >> 11, trow = m & 2047;
            size_t obase = (((size_t)(bb * NH + h)) * 2048 + trow) * 64;
#pragma unroll
            for (int j = 0; j < 4; ++j) {
                float v = acc[i][j][r] + bqkv[colbase + j * 16 + n];
                dst[obase + j * 16 + n] = f2bf(v * sc);
            }
        }
    }
}

// =====================================================================
// transpose_v: V [bh][2048][64] bf16 -> Vt [bh][64][2048] bf16
// =====================================================================
__global__ __launch_bounds__(256) void transpose_v(
    const u16* __restrict__ V, u16* __restrict__ Vt)
{
    __shared__ u16 tile[64 * 82];
    const int bh = blockIdx.y, t0 = blockIdx.x * 64;
    const int t = threadIdx.x;
    const u16* src = V + (size_t)bh * 131072 + (size_t)t0 * 64;
    u16* dst = Vt + (size_t)bh * 131072 + t0;
#pragma unroll
    for (int p = 0; p < 2; ++p) {
        int id = t + p * 256;
        int row = id >> 3, seg = id & 7;
        ushort4 u0 = *reinterpret_cast<const ushort4*>(&src[row * 64 + seg * 8]);
        ushort4 u1 = *reinterpret_cast<const ushort4*>(&src[row * 64 + seg * 8 + 4]);
        u16* tp = &tile[row * 82 + seg * 8];
        tp[0] = u0.x; tp[1] = u0.y; tp[2] = u0.z; tp[3] = u0.w;
        tp[4] = u1.x; tp[5] = u1.y; tp[6] = u1.z; tp[7] = u1.w;
    }
    __syncthreads();
#pragma unroll
    for (int p = 0; p < 2; ++p) {
        int id = t + p * 256;
        int d = id >> 3, ks = id & 7;
        u16 u[8];
#pragma unroll
        for (int j = 0; j < 8; ++j) u[j] = tile[(ks * 8 + j) * 82 + d];
        *reinterpret_cast<ushort4*>(&dst[(size_t)d * 2048 + ks * 8])     = make_ushort4(u[0], u[1], u[2], u[3]);
        *reinterpret_cast<ushort4*>(&dst[(size_t)d * 2048 + ks * 8 + 4]) = make_ushort4(u[4], u[5], u[6], u[7]);
    }
}

// =====================================================================
// attn_mfma v5: triangular PAIRING + 128-k stages + Ps-in-Qs alias.
// Block (i,bh) processes q-tiles {15-i, i} sequentially: EVERY block does
// exactly 17 k-stages (perfect balance). grid (8,64) = 512 blocks = 2/CU,
// all co-resident. Each stage: 2 barriers, 2x 64-k subtiles (64 MFMA).
// LDS 48 KB: QPs 16 (Q frags, then per-wave P^T strips in own rows),
//            Ks 16 (128k x 64d), Vs 16 (64d x 128k). All XOR-chunk-swizzled.
// =====================================================================
__global__ __launch_bounds__(256, 2) void attn_mfma(
    const u16* __restrict__ Q, const u16* __restrict__ K,
    const u16* __restrict__ Vt, u16* __restrict__ Y)
{
    const int pairi = blockIdx.x;          // 0..7
    const int bh = blockIdx.y;
    const int b = bh >> 4, h = bh & 15;
    const size_t base = (size_t)bh * (T_ * HD);

    __shared__ __attribute__((aligned(16))) u16 QPs[128 * 64];
    __shared__ __attribute__((aligned(16))) u16 Ks[128 * 64];
    __shared__ __attribute__((aligned(16))) u16 Vs[64 * 128];

    const int t = threadIdx.x, lane = t & 63, w = t >> 6;
    const int n = lane & 15, quad = lane >> 4;
    const int tmask = t & ~63;

    for (int ph = 0; ph < 2; ++ph) {
        const int qt = ph ? pairi : 15 - pairi;   // big tile first
        const int q0 = qt * 128;
        const int qw_lo = q0 + w * 32;
        const int qw_hi = qw_lo + 31;

        __syncthreads();   // prior phase's QPs/Ks/Vs readers done

        // issue Q DMA (1024 chunks; completes at first in-loop barrier)
#pragma unroll
        for (int p = 0; p < 4; ++p) {
            int id = t + p * 256;
            int row = id >> 3, c = (id & 7) ^ (row & 7);
            gl2lds16(&Q[base + (size_t)(q0 + row) * 64 + c * 8], &QPs[(tmask + p * 256) * 8]);
        }

        f32x4 o[2][4] = {};
        float mst[2] = {-1e30f, -1e30f}, lst[2] = {0.f, 0.f};
        bf16x8 qa[2][2];

        const int nst = qt + 1;    // 128-k stages
        for (int st = 0; st < nst; ++st) {
            const int k0 = st * 128;
            __syncthreads();   // prior-stage Ks/Vs readers done
            // K: 128 rows x 64 d = 1024 chunks
#pragma unroll
            for (int p = 0; p < 4; ++p) {
                int id = t + p * 256;
                int row = id >> 3, c = (id & 7) ^ (row & 7);
                gl2lds16(&K[base + (size_t)(k0 + row) * 64 + c * 8], &Ks[(tmask + p * 256) * 8]);
            }
            // Vt: 64 d rows x 128 k = 1024 chunks (16 chunks/row)
#pragma unroll
            for (int p = 0; p < 4; ++p) {
                int id = t + p * 256;
                int row = id >> 4, cs = id & 15, c = cs ^ (row & 7);
                gl2lds16(&Vt[base + (size_t)row * 2048 + k0 + c * 8], &Vs[(tmask + p * 256) * 8]);
            }
            __syncthreads();   // all staging DMA complete (incl Q on st==0)

            if (st == 0) {     // Q frags: wave reads ONLY its own 32 rows
#pragma unroll
                for (int nt2 = 0; nt2 < 2; ++nt2)
#pragma unroll
                    for (int dh = 0; dh < 2; ++dh) {
                        int row = w * 32 + nt2 * 16 + n;
                        int slot = (quad + dh * 4) ^ (n & 7);
                        qa[nt2][dh] = *reinterpret_cast<const bf16x8*>(&QPs[row * 64 + slot * 8]);
                    }
            }

#pragma unroll
            for (int sub = 0; sub < 2; ++sub) {
                const int k0s = k0 + sub * 64;
                if (k0s > qw_hi) continue;   // fully masked for this wave
                const u16* Kc = &Ks[sub * 64 * 64];

                // ---- S^T = K Q^T : strip [64 k][32 q] ----
                bf16x8 kf[4][2];
#pragma unroll
                for (int mt = 0; mt < 4; ++mt)
#pragma unroll
                    for (int dh = 0; dh < 2; ++dh) {
                        int row = mt * 16 + n;
                        int slot = (quad + dh * 4) ^ (n & 7);
                        kf[mt][dh] = *reinterpret_cast<const bf16x8*>(&Kc[row * 64 + slot * 8]);
                    }
                f32x4 s2[2][4] = {};
#pragma unroll
                for (int nt2 = 0; nt2 < 2; ++nt2)
#pragma unroll
                    for (int mt = 0; mt < 4; ++mt)
#pragma unroll
                        for (int dh = 0; dh < 2; ++dh)
                            s2[nt2][mt] = MFMA_BF16(kf[mt][dh], qa[nt2][dh], s2[nt2][mt]);

                // causal mask: needed when subtile's max k exceeds wave's LOWEST q
                if (k0s + 63 > qw_lo) {
#pragma unroll
                    for (int nt2 = 0; nt2 < 2; ++nt2) {
                        int qrel = (qw_lo + nt2 * 16 + n) - k0s;
#pragma unroll
                        for (int mt = 0; mt < 4; ++mt)
#pragma unroll
                            for (int r = 0; r < 4; ++r)
                                if (mt * 16 + quad * 4 + r > qrel) s2[nt2][mt][r] = -1e30f;
                    }
                }

                // ---- lane-local online softmax (lane owns q = nt2*16 + n) ----
                float alpha[2];
#pragma unroll
                for (int nt2 = 0; nt2 < 2; ++nt2) {
                    float mx = -1e30f;
#pragma unroll
                    for (int mt = 0; mt < 4; ++mt)
                        mx = fmaxf(mx, fmaxf(fmaxf(s2[nt2][mt][0], s2[nt2][mt][1]),
                                             fmaxf(s2[nt2][mt][2], s2[nt2][mt][3])));
                    mx = fmaxf(mx, __shfl_xor(mx, 16, 64));
                    mx = fmaxf(mx, __shfl_xor(mx, 32, 64));
                    float mnew = fmaxf(mst[nt2], mx);
                    alpha[nt2] = __expf(mst[nt2] - mnew);
                    float rs = 0.f;
#pragma unroll
                    for (int mt = 0; mt < 4; ++mt)
#pragma unroll
                        for (int r = 0; r < 4; ++r) {
                            float p = __expf(s2[nt2][mt][r] - mnew);
                            s2[nt2][mt][r] = p;
                            rs += p;
                        }
                    rs += __shfl_xor(rs, 16, 64);
                    rs += __shfl_xor(rs, 32, 64);
                    lst[nt2] = lst[nt2] * alpha[nt2] + rs;
                    mst[nt2] = mnew;
                }

                // ---- P^T -> wave's own QPs rows (XOR swizzle; validated r6) ----
#pragma unroll
                for (int nt2 = 0; nt2 < 2; ++nt2)
#pragma unroll
                    for (int mt = 0; mt < 4; ++mt) {
                        int kc = mt * 2 + (quad >> 1);
                        int off = (w * 32 + nt2 * 16 + n) * 64 + (kc ^ (n & 7)) * 8 + (quad & 1) * 4;
                        *reinterpret_cast<bf16x4*>(&QPs[off]) = pack4(s2[nt2][mt]);
                    }

                // ---- rescale O, then O^T += V^T P^T ----
#pragma unroll
                for (int nt2 = 0; nt2 < 2; ++nt2)
#pragma unroll
                    for (int dt = 0; dt < 4; ++dt)
                        o[nt2][dt] *= alpha[nt2];

                bf16x8 pf[2][2];
#pragma unroll
                for (int nt2 = 0; nt2 < 2; ++nt2)
#pragma unroll
                    for (int kh = 0; kh < 2; ++kh) {
                        int kc = kh * 4 + quad;
                        int off = (w * 32 + nt2 * 16 + n) * 64 + (kc ^ (n & 7)) * 8;
                        pf[nt2][kh] = *reinterpret_cast<const bf16x8*>(&QPs[off]);
                    }
                bf16x8 vf[4][2];
#pragma unroll
                for (int dt = 0; dt < 4; ++dt)
#pragma unroll
                    for (int kh = 0; kh < 2; ++kh) {
                        int row = dt * 16 + n;
                        int slot = ((sub * 8 + kh * 4 + quad) ^ (n & 7));
                        vf[dt][kh] = *reinterpret_cast<const bf16x8*>(&Vs[row * 128 + slot * 8]);
                    }
#pragma unroll
                for (int nt2 = 0; nt2 < 2; ++nt2)
#pragma unroll
                    for (int dt = 0; dt < 4; ++dt)
#pragma unroll
                        for (int kh = 0; kh < 2; ++kh)
                            o[nt2][dt] = MFMA_BF16(vf[dt][kh], pf[nt2][kh], o[nt2][dt]);
            }
        }

        // epilogue: Y[b,q,h,d] = O^T / l
#pragma unroll
        for (int nt2 = 0; nt2 < 2; ++nt2) {
            float inv = 1.f / lst[nt2];
            int qg = qw_lo + nt2 * 16 + n;
            size_t ob = (((size_t)(b * 2048 + qg)) * NH + h) * 64;
#pragma unroll
            for (int dt = 0; dt < 4; ++dt) {
                ushort4 stv = make_ushort4(f2bf(o[nt2][dt][0] * inv), f2bf(o[nt2][dt][1] * inv),
                                           f2bf(o[nt2][dt][2] * inv), f2bf(o[nt2][dt][3] * inv));
                *reinterpret_cast<ushort4*>(&Y[ob + dt * 16 + quad * 4]) = stv;
            }
        }
    }
}

// =====================================================================
// proj_gemm_mfma (round-3 proven version): BK=32, gl2lds16. grid (8,64).
// =====================================================================
__global__ __launch_bounds__(256, 3) void proj_gemm_mfma(
    const u16* __restrict__ A, const u16* __restrict__ BT,
    const float* __restrict__ bias, float* __restrict__ out)
{
    __shared__ __attribute__((aligned(16))) u16 As[128 * 32];
    __shared__ __attribute__((aligned(16))) u16 Bs[128 * 32];

    const int t = threadIdx.x, lane = t & 63, w = t >> 6;
    const int n = lane & 15, quad = lane >> 4;
    const int wr = w >> 1, wc = w & 1;
    const int m0 = blockIdx.y * 128, n0 = blockIdx.x * 128;
    const int tmask = t & ~63;

    f32x4 acc[4][4] = {};

    for (int k0 = 0; k0 < 1024; k0 += 32) {
        __syncthreads();
#pragma unroll
        for (int p = 0; p < 2; ++p) {
            int id = t + p * 256;
            int row = id >> 2, c = (id & 3) ^ (row & 3);
            gl2lds16(&A[(size_t)(m0 + row) * 1024 + k0 + c * 8], &As[(tmask + p * 256) * 8]);
            gl2lds16(&BT[(size_t)(n0 + row) * 1024 + k0 + c * 8], &Bs[(tmask + p * 256) * 8]);
        }
        __syncthreads();

        const int slot = (quad ^ (n & 3)) * 8;
        bf16x8 a[4], b[4];
#pragma unroll
        for (int i = 0; i < 4; ++i)
            a[i] = *reinterpret_cast<const bf16x8*>(&As[(wr * 64 + i * 16 + n) * 32 + slot]);
#pragma unroll
        for (int j = 0; j < 4; ++j)
            b[j] = *reinterpret_cast<const bf16x8*>(&Bs[(wc * 64 + j * 16 + n) * 32 + slot]);
#pragma unroll
        for (int i = 0; i < 4; ++i)
#pragma unroll
            for (int j = 0; j < 4; ++j)
                acc[i][j] = MFMA_BF16(a[i], b[j], acc[i][j]);
    }

#pragma unroll
    for (int i = 0; i < 4; ++i)
#pragma unroll
        for (int r = 0; r < 4; ++r) {
            int m = m0 + wr * 64 + i * 16 + quad * 4 + r;
#pragma unroll
            for (int j = 0; j < 4; ++j) {
                int col = n0 + wc * 64 + j * 16 + n;
                out[(size_t)m * 1024 + col] = acc[i][j][r] + bias[col];
            }
        }
}

// =====================================================================
// Workspace overlay (<= 64 MB ws + d_out used as pre-proj scratch):
//   ws [0,16M): Q      ... later wpT (after attn)
//   ws [16,32M): K
//   ws [32,48M): V     ... later Y (after transpose_v)
//   ws [48,54M): wqT   ... [48,64M): Vt (after qkv)
//   d_out [0,16M): xb (bf16 x) — dead before proj writes d_out
// =====================================================================
extern "C" void kernel_launch(void* const* d_in, const int* in_sizes, int n_in,
                              void* d_out, int out_size, void* d_ws, size_t ws_size,
                              hipStream_t stream) {
    const float* x      = (const float*)d_in[0];
    const float* w_qkv  = (const float*)d_in[1];
    const float* b_qkv  = (const float*)d_in[2];
    const float* w_proj = (const float*)d_in[3];
    const float* b_proj = (const float*)d_in[4];
    float* out = (float*)d_out;

    const size_t E16 = 8388608;
    u16* ws  = (u16*)d_ws;
    u16* Qp  = ws;
    u16* Kp  = ws + E16;
    u16* Vp  = ws + 2 * E16;
    u16* wqT = ws + 3 * E16;
    u16* VtP = ws + 3 * E16;
    u16* Yp  = ws + 2 * E16;
    u16* wpT = ws;
    u16* xb  = (u16*)d_out;                // scratch inside d_out, dead before proj

    cast_x<<<dim3(4096), 256, 0, stream>>>(x, xb);
    transpose_w<<<dim3(96, 32), dim3(32, 8), 0, stream>>>(w_qkv, wqT, 1024, 3072);
    qkv_gemm_mfma<<<dim3(24, 64), 256, 0, stream>>>(xb, wqT, b_qkv, Qp, Kp, Vp);
    transpose_v<<<dim3(32, 64), 256, 0, stream>>>(Vp, VtP);
    attn_mfma<<<dim3(8, 64), 256, 0, stream>>>(Qp, Kp, VtP, Yp);
    transpose_w<<<dim3(32, 32), dim3(32, 8), 0, stream>>>(w_proj, wpT, 1024, 1024);
    proj_gemm_mfma<<<dim3(8, 64), 256, 0, stream>>>(Yp, wpT, b_proj, out);
}